// Round 5
// baseline (421.857 us; speedup 1.0000x reference)
//
#include <hip/hip_runtime.h>
#include <hip/hip_bf16.h>
#include <stdint.h>

typedef _Float16 f16;
typedef _Float16 f16x4 __attribute__((ext_vector_type(4)));
typedef _Float16 f16x8 __attribute__((ext_vector_type(8)));
typedef float f32x4 __attribute__((ext_vector_type(4)));

// async global->LDS copy, 16B per lane. LDS dest must be wave-uniform base + lane*16.
#define ASYNC_COPY16(gsrc, ldst)                                                   \
    __builtin_amdgcn_global_load_lds(                                              \
        (__attribute__((address_space(1))) void*)(gsrc),                           \
        (__attribute__((address_space(3))) void*)(ldst), 16, 0, 0)

// bank-quad-perfect XOR swizzle for 64B rows (BK=32 f16): 2-way floor on ds_read
__device__ __forceinline__ int swz(int row) { return (row & 3) ^ ((row >> 2) & 3); }

// ---------------------------------------------------------------------------
// fp32 -> f16 converts (y, W1, W2) in one launch; block 0 also zeros dotv.
// ---------------------------------------------------------------------------
__global__ __launch_bounds__(256) void cvt3_f32_to_f16(const float* __restrict__ y,
                                                       const float* __restrict__ W1,
                                                       const float* __restrict__ W2,
                                                       f16* __restrict__ yb,
                                                       f16* __restrict__ w1b,
                                                       f16* __restrict__ w2b,
                                                       float* __restrict__ dotv,
                                                       int Brows, int nY4, int nW4) {
    if (blockIdx.x == 0) {
        for (int j = threadIdx.x; j < Brows; j += 256) dotv[j] = 0.f;
    }
    int i = blockIdx.x * 256 + threadIdx.x;
    const float* src;
    f16* dst;
    int off;
    if (i < nY4) {
        src = y; dst = yb; off = i;
    } else if (i < nY4 + nW4) {
        src = W1; dst = w1b; off = i - nY4;
    } else {
        src = W2; dst = w2b; off = i - nY4 - nW4;
        if (off >= nW4) return;
    }
    float4 v = ((const float4*)src)[off];
    f16x4 o;
    o.x = (f16)v.x; o.y = (f16)v.y; o.z = (f16)v.z; o.w = (f16)v.w;
    ((f16x4*)dst)[off] = o;
}

__global__ __launch_bounds__(256) void cvt_f32_to_f16(const float* __restrict__ in,
                                                      f16* __restrict__ out, int n4) {
    int i = blockIdx.x * 256 + threadIdx.x;
    if (i >= n4) return;
    float4 v = ((const float4*)in)[i];
    f16x4 o;
    o.x = (f16)v.x; o.y = (f16)v.y; o.z = (f16)v.z; o.w = (f16)v.w;
    ((f16x4*)out)[i] = o;
}

// ---------------------------------------------------------------------------
// GEMM1: h = f16(A(MxK) @ B(NxK)^T + bias). Tile 128x128, BK=32, dbuf LDS
// (32 KB total), ONE barrier/iter. 128 threads = 2 waves; each wave computes
// 128(M) x 64(N) as 8x4 16x16x32 MFMAs. Grid M/128 x N/128 = 512 blocks ->
// 4 blocks/CU (4 independent barrier domains vs round-3's 2).
// ---------------------------------------------------------------------------
__global__ __launch_bounds__(128, 2) void gemm1_2w(const f16* __restrict__ A,
                                                   const f16* __restrict__ Bm,
                                                   const float* __restrict__ bias,
                                                   f16* __restrict__ Cout,
                                                   int M, int N, int K) {
    constexpr int BK = 32;
    __shared__ __align__(16) f16 sA[2][128 * BK];  // 2 x 8 KB
    __shared__ __align__(16) f16 sB[2][128 * BK];  // 2 x 8 KB

    const int tid  = threadIdx.x;   // 0..127
    const int lane = tid & 63;
    const int wave = tid >> 6;      // 0..1 = N-half

    const int bm = blockIdx.y * 128;
    const int bn = blockIdx.x * 128;

    const f16* Aptr = A + (size_t)bm * K;
    const f16* Bptr = Bm + (size_t)bn * K;

    // staging: granule idx = j*128 + t  ->  row = j*32 + (t>>2), seg-slot = t&3.
    // LDS halves offset = idx*8 (linear, as global_load_lds requires).
    // content fetched = global seg (slot ^ swz(row)).
    const int srow = tid >> 2;      // 0..31
    const int sslot = tid & 3;

    f32x4 acc[8][4] = {};

    const int quad = lane >> 4;
    const int l16  = lane & 15;

    const int iters = K / BK;

    // prologue: buf 0
#pragma unroll
    for (int j = 0; j < 4; j++) {
        const int row = j * 32 + srow;
        const int seg = sslot ^ swz(row);
        ASYNC_COPY16(Aptr + (size_t)row * K + seg * 8, &sA[0][j * 1024 + tid * 8]);
    }
#pragma unroll
    for (int j = 0; j < 4; j++) {
        const int row = j * 32 + srow;
        const int seg = sslot ^ swz(row);
        ASYNC_COPY16(Bptr + (size_t)row * K + seg * 8, &sB[0][j * 1024 + tid * 8]);
    }

    int cur = 0;
    for (int it = 0; it < iters; ++it) {
        __syncthreads();  // drains vmcnt: buf[cur] ready

        if (it + 1 < iters) {
            const int k0 = (it + 1) * BK;
#pragma unroll
            for (int j = 0; j < 4; j++) {
                const int row = j * 32 + srow;
                const int seg = sslot ^ swz(row);
                ASYNC_COPY16(Aptr + (size_t)row * K + k0 + seg * 8,
                             &sA[cur ^ 1][j * 1024 + tid * 8]);
            }
#pragma unroll
            for (int j = 0; j < 4; j++) {
                const int row = j * 32 + srow;
                const int seg = sslot ^ swz(row);
                ASYNC_COPY16(Bptr + (size_t)row * K + k0 + seg * 8,
                             &sB[cur ^ 1][j * 1024 + tid * 8]);
            }
        }

        f16x8 af[8], bf[4];
#pragma unroll
        for (int mi = 0; mi < 8; mi++) {
            const int row = mi * 16 + l16;
            const int sl = quad ^ swz(row);
            af[mi] = *(const f16x8*)&sA[cur][row * BK + sl * 8];
        }
#pragma unroll
        for (int ni = 0; ni < 4; ni++) {
            const int row = wave * 64 + ni * 16 + l16;
            const int sl = quad ^ swz(row);
            bf[ni] = *(const f16x8*)&sB[cur][row * BK + sl * 8];
        }
#pragma unroll
        for (int mi = 0; mi < 8; mi++)
#pragma unroll
            for (int ni = 0; ni < 4; ni++)
                acc[mi][ni] = __builtin_amdgcn_mfma_f32_16x16x32_f16(af[mi], bf[ni],
                                                                     acc[mi][ni], 0, 0, 0);
        cur ^= 1;  // single barrier/iter; next barrier protects buf reuse
    }

    // epilogue: C/D layout col = lane&15, row = quad*4 + reg
#pragma unroll
    for (int ni = 0; ni < 4; ni++) {
        const int col = bn + wave * 64 + ni * 16 + l16;
        const float bv = bias[col];
#pragma unroll
        for (int mi = 0; mi < 8; mi++) {
            const int row0 = bm + mi * 16 + quad * 4;
#pragma unroll
            for (int r = 0; r < 4; r++)
                Cout[(size_t)(row0 + r) * N + col] = (f16)(acc[mi][ni][r] + bv);
        }
    }
}

// ---------------------------------------------------------------------------
// GEMM2 split-K: P[z] = A(MxK2 slice) @ B^T (+bias if z==0), fp32 out, fused
// per-row partial dot(y, P) atomicAdd into dotv. Tile 128x128, 4 waves (2x2),
// BK=32 dbuf, one barrier/iter. Grid (N/128, M/128, SPLITK) -> 1024 blocks,
// 4 blocks/CU, 16 waves/CU.
// ---------------------------------------------------------------------------
__global__ __launch_bounds__(256, 4) void gemm2_sk(const f16* __restrict__ A,
                                                   const f16* __restrict__ Bm,
                                                   const float* __restrict__ bias,
                                                   float* __restrict__ P,
                                                   const float* __restrict__ Yf,
                                                   float* __restrict__ dotv,
                                                   int M, int N, int K, int K2) {
    constexpr int BK = 32;
    __shared__ __align__(16) f16 sA[2][128 * BK];
    __shared__ __align__(16) f16 sB[2][128 * BK];

    const int tid   = threadIdx.x;
    const int lane  = tid & 63;
    const int wave  = tid >> 6;
    const int waveM = wave >> 1;
    const int waveN = wave & 1;

    const int bm = blockIdx.y * 128;
    const int bn = blockIdx.x * 128;
    const int z  = blockIdx.z;
    const int kbase = z * K2;

    float* Pz = P + (size_t)z * M * N;

    const f16* Aptr = A + (size_t)bm * K + kbase;
    const f16* Bptr = Bm + (size_t)bn * K + kbase;

    // staging: granule idx = j*256 + t -> row = j*64 + (t>>2), slot = t&3
    const int srow = tid >> 2;      // 0..63
    const int sslot = tid & 3;

    f32x4 acc[4][4] = {};

    const int quad = lane >> 4;
    const int l16  = lane & 15;

    const int iters = K2 / BK;

#pragma unroll
    for (int j = 0; j < 2; j++) {
        const int row = j * 64 + srow;
        const int seg = sslot ^ swz(row);
        ASYNC_COPY16(Aptr + (size_t)row * K + seg * 8, &sA[0][j * 2048 + tid * 8]);
    }
#pragma unroll
    for (int j = 0; j < 2; j++) {
        const int row = j * 64 + srow;
        const int seg = sslot ^ swz(row);
        ASYNC_COPY16(Bptr + (size_t)row * K + seg * 8, &sB[0][j * 2048 + tid * 8]);
    }

    int cur = 0;
    for (int it = 0; it < iters; ++it) {
        __syncthreads();

        if (it + 1 < iters) {
            const int k0 = (it + 1) * BK;
#pragma unroll
            for (int j = 0; j < 2; j++) {
                const int row = j * 64 + srow;
                const int seg = sslot ^ swz(row);
                ASYNC_COPY16(Aptr + (size_t)row * K + k0 + seg * 8,
                             &sA[cur ^ 1][j * 2048 + tid * 8]);
            }
#pragma unroll
            for (int j = 0; j < 2; j++) {
                const int row = j * 64 + srow;
                const int seg = sslot ^ swz(row);
                ASYNC_COPY16(Bptr + (size_t)row * K + k0 + seg * 8,
                             &sB[cur ^ 1][j * 2048 + tid * 8]);
            }
        }

        f16x8 af[4], bf[4];
#pragma unroll
        for (int mi = 0; mi < 4; mi++) {
            const int row = waveM * 64 + mi * 16 + l16;
            const int sl = quad ^ swz(row);
            af[mi] = *(const f16x8*)&sA[cur][row * BK + sl * 8];
        }
#pragma unroll
        for (int ni = 0; ni < 4; ni++) {
            const int row = waveN * 64 + ni * 16 + l16;
            const int sl = quad ^ swz(row);
            bf[ni] = *(const f16x8*)&sB[cur][row * BK + sl * 8];
        }
#pragma unroll
        for (int mi = 0; mi < 4; mi++)
#pragma unroll
            for (int ni = 0; ni < 4; ni++)
                acc[mi][ni] = __builtin_amdgcn_mfma_f32_16x16x32_f16(af[mi], bf[ni],
                                                                     acc[mi][ni], 0, 0, 0);
        cur ^= 1;
    }

    // epilogue: store fp32 partial, fused partial dot
#pragma unroll
    for (int mi = 0; mi < 4; mi++) {
#pragma unroll
        for (int r = 0; r < 4; r++) {
            const int row = bm + waveM * 64 + mi * 16 + quad * 4 + r;
            float rowsum = 0.f;
#pragma unroll
            for (int ni = 0; ni < 4; ni++) {
                const int col = bn + waveN * 64 + ni * 16 + l16;
                float v = acc[mi][ni][r] + (z == 0 ? bias[col] : 0.f);
                Pz[(size_t)row * N + col] = v;
                rowsum += v * Yf[(size_t)row * N + col];
            }
#pragma unroll
            for (int off = 8; off > 0; off >>= 1)
                rowsum += __shfl_xor(rowsum, off, 64);
            if (l16 == 0) atomicAdd(&dotv[row], rowsum);
        }
    }
}

// ---------------------------------------------------------------------------
// finish: out = y * (P0 + P1 - dot[row]); P1 may be null (unsplit path).
// ---------------------------------------------------------------------------
__global__ __launch_bounds__(256) void finish_replicator(const float* __restrict__ y,
                                                         const float* __restrict__ P0,
                                                         const float* __restrict__ P1,
                                                         float* __restrict__ out,
                                                         const float* __restrict__ dotv,
                                                         int N) {
    const int row = blockIdx.x;
    const float dot = dotv[row];
    const float4* y4 = (const float4*)(y + (size_t)row * N);
    const float4* p04 = (const float4*)(P0 + (size_t)row * N);
    float4* o4 = (float4*)(out + (size_t)row * N);
    const int n4 = N / 4;
    if (P1) {
        const float4* p14 = (const float4*)(P1 + (size_t)row * N);
        for (int i = threadIdx.x; i < n4; i += 256) {
            float4 a = y4[i], b0 = p04[i], b1 = p14[i];
            float4 r;
            r.x = a.x * (b0.x + b1.x - dot);
            r.y = a.y * (b0.y + b1.y - dot);
            r.z = a.z * (b0.z + b1.z - dot);
            r.w = a.w * (b0.w + b1.w - dot);
            o4[i] = r;
        }
    } else {
        for (int i = threadIdx.x; i < n4; i += 256) {
            float4 a = y4[i], b0 = p04[i];
            float4 r;
            r.x = a.x * (b0.x - dot);
            r.y = a.y * (b0.y - dot);
            r.z = a.z * (b0.z - dot);
            r.w = a.w * (b0.w - dot);
            o4[i] = r;
        }
    }
}

extern "C" void kernel_launch(void* const* d_in, const int* in_sizes, int n_in,
                              void* d_out, int out_size, void* d_ws, size_t ws_size,
                              hipStream_t stream) {
    // inputs: 0=t(1), 1=y(B*N), 2=W1(N*N), 3=b1(N), 4=W2(N*N), 5=b2(N)
    const float* y  = (const float*)d_in[1];
    const float* W1 = (const float*)d_in[2];
    const float* b1 = (const float*)d_in[3];
    const float* W2 = (const float*)d_in[4];
    const float* b2 = (const float*)d_in[5];

    const int N = in_sizes[3];            // 4096
    const int B = in_sizes[1] / N;        // 2048
    float* out = (float*)d_out;

    const size_t szY = (size_t)B * N;
    const size_t szW = (size_t)N * N;
    const int yn4 = (int)(szY / 4);
    const int wn4 = (int)(szW / 4);

    dim3 g1(N / 128, B / 128);            // 512 blocks

    const size_t f16_part = (szY + 2 * szW + szY) * sizeof(f16);   // yb|w1b|w2b|hb
    const size_t need_big = f16_part + 2 * szY * sizeof(float) + (size_t)B * 4;
    const size_t need_mid = f16_part + (size_t)B * 4;

    if (ws_size >= need_big) {
        f16* yb  = (f16*)d_ws;
        f16* w1b = yb + szY;
        f16* w2b = w1b + szW;
        f16* hb  = w2b + szW;
        float* P  = (float*)(hb + szY);          // P0 | P1
        float* dotv = P + 2 * szY;

        const int tot4 = yn4 + 2 * wn4;
        cvt3_f32_to_f16<<<(tot4 + 255) / 256, 256, 0, stream>>>(y, W1, W2, yb, w1b, w2b,
                                                                dotv, B, yn4, wn4);
        gemm1_2w<<<g1, 128, 0, stream>>>(yb, w1b, b1, hb, B, N, N);
        dim3 g2(N / 128, B / 128, 2);
        gemm2_sk<<<g2, 256, 0, stream>>>(hb, w2b, b2, P, y, dotv, B, N, N, N / 2);
        finish_replicator<<<B, 256, 0, stream>>>(y, P, P + szY, out, dotv, N);
    } else if (ws_size >= need_mid) {
        f16* yb  = (f16*)d_ws;
        f16* w1b = yb + szY;
        f16* w2b = w1b + szW;
        f16* hb  = w2b + szW;
        float* dotv = (float*)(hb + szY);

        const int tot4 = yn4 + 2 * wn4;
        cvt3_f32_to_f16<<<(tot4 + 255) / 256, 256, 0, stream>>>(y, W1, W2, yb, w1b, w2b,
                                                                dotv, B, yn4, wn4);
        gemm1_2w<<<g1, 128, 0, stream>>>(yb, w1b, b1, hb, B, N, N);
        dim3 g2(N / 128, B / 128, 1);
        gemm2_sk<<<g2, 256, 0, stream>>>(hb, w2b, b2, out, y, dotv, B, N, N, N);
        finish_replicator<<<B, 256, 0, stream>>>(y, out, nullptr, out, dotv, N);
    } else {
        // minimal ws: reuse one weight buffer
        f16* yb = (f16*)d_ws;
        f16* wb = yb + szY;
        f16* hb = wb + szW;
        float* dotv = (float*)(hb + szY);

        cvt_f32_to_f16<<<yn4 / 256, 256, 0, stream>>>(y, yb, yn4);
        cvt_f32_to_f16<<<wn4 / 256, 256, 0, stream>>>(W1, wb, wn4);
        hipMemsetAsync(dotv, 0, (size_t)B * 4, stream);
        gemm1_2w<<<g1, 128, 0, stream>>>(yb, wb, b1, hb, B, N, N);
        cvt_f32_to_f16<<<wn4 / 256, 256, 0, stream>>>(W2, wb, wn4);
        dim3 g2(N / 128, B / 128, 1);
        gemm2_sk<<<g2, 256, 0, stream>>>(hb, wb, b2, out, y, dotv, B, N, N, N);
        finish_replicator<<<B, 256, 0, stream>>>(y, out, nullptr, out, dotv, N);
    }
}